// Round 18
// baseline (236.176 us; speedup 1.0000x reference)
//
#include <hip/hip_runtime.h>
#include <stdint.h>

// ---------- types ----------
typedef __attribute__((ext_vector_type(8))) __bf16 bf16x8;
typedef __attribute__((ext_vector_type(4))) float f32x4;
typedef __attribute__((ext_vector_type(8))) unsigned short u16x8;
typedef __attribute__((ext_vector_type(4))) unsigned short u16x4;

#define MFMA16(a, b, c) __builtin_amdgcn_mfma_f32_16x16x32_bf16((a), (b), (c), 0, 0, 0)

__device__ __forceinline__ void glds16(const void* g, void* l) {
  __builtin_amdgcn_global_load_lds(
      (const __attribute__((address_space(1))) void*)(uintptr_t)g,
      (__attribute__((address_space(3))) void*)(uint32_t)(uintptr_t)l,
      16, 0, 0);
}

__device__ __forceinline__ unsigned short f2bf(float f) {
  union { float f; unsigned u; } v; v.f = f;
  unsigned r = v.u + 0x7FFFu + ((v.u >> 16) & 1u);
  return (unsigned short)(r >> 16);
}
__device__ __forceinline__ float bf2f(unsigned short s) {
  union { unsigned u; float f; } v; v.u = ((unsigned)s) << 16;
  return v.f;
}
__device__ __forceinline__ bf16x8 as_bf16x8(u16x8 v) {
  union { u16x8 u; bf16x8 b; } c; c.u = v; return c.b;
}

// ---------- problem constants ----------
#define B_ 32
#define N_ 512
#define C_ 1024
#define H_ 16
#define D_ 64
#define K_ C_                // 1024

#define NX8 2097152          // x elements / 8
#define NW8 393216           // w elements / 8
#define NT8 2048             // table entries / 8

// ---------- fused prep: x->bf16 | w->bf16 | rope float2 table, one launch ----------
__global__ __launch_bounds__(256) void prep_kernel(
    const float* __restrict__ x, const float* __restrict__ w,
    unsigned short* __restrict__ xb, unsigned short* __restrict__ wb,
    float2* __restrict__ sc_t) {
  const int i = blockIdx.x * 256 + threadIdx.x;
  if (i < NX8 + NW8) {
    const float* src = (i < NX8) ? x : w;
    unsigned short* dst = (i < NX8) ? xb : wb;
    const int k = (i < NX8) ? i : i - NX8;
    const float4* p = reinterpret_cast<const float4*>(src) + (size_t)k * 2;
    float4 a = p[0], b = p[1];
    u16x8 o;
    o[0] = f2bf(a.x); o[1] = f2bf(a.y); o[2] = f2bf(a.z); o[3] = f2bf(a.w);
    o[4] = f2bf(b.x); o[5] = f2bf(b.y); o[6] = f2bf(b.z); o[7] = f2bf(b.w);
    *reinterpret_cast<u16x8*>(dst + (size_t)k * 8) = o;
  } else if (i < NX8 + NW8 + NT8) {
    const int base = (i - NX8 - NW8) * 8;
#pragma unroll
    for (int e = 0; e < 8; ++e) {
      const int idx = base + e;           // n*32 + ip
      const int n = idx >> 5, ip = idx & 31;
      const float div = expf(-(2.0f * (float)ip) * (9.210340371976184f / 64.0f));
      const float ang = (float)n * div;
      sc_t[idx] = make_float2(sinf(ang), cosf(ang));
    }
  }
}

// ---------- QKV GEMM: 256x256, BK=64, minimum 2-phase (unchanged from R17) ----------
#define STAGE_T(bi, uu)                                                \
  do {                                                                 \
    _Pragma("unroll") for (int h_ = 0; h_ < 4; ++h_) {                 \
      glds16(aS[h_] + (size_t)(uu) * 64, &lds[bi][h_ * 4096 + t * 8]); \
      glds16(bS[h_] + (size_t)(uu) * 64,                               \
             &lds[bi][16384 + h_ * 4096 + t * 8]);                     \
    }                                                                  \
  } while (0)

__global__ __launch_bounds__(512, 2) void qkv_gemm_kernel(
    const unsigned short* __restrict__ xb, const unsigned short* __restrict__ wb,
    const float* __restrict__ bias,
    unsigned short* __restrict__ Qb, unsigned short* __restrict__ Kb,
    unsigned short* __restrict__ Vtb,
    const float2* __restrict__ sc_t) {
  __shared__ unsigned short lds[2][32768];  // 128 KB
  const int t = threadIdx.x;
  const int wv = t >> 6, l = t & 63;
  const int wr = wv >> 2, wc = wv & 3;   // 2 x 4 waves, wave tile 128x64
  const int lq = l >> 4, lr = l & 15;

  // XCD-chunked bijective swizzle (768 = 8 * 96)
  const int bid = (blockIdx.x & 7) * 96 + (blockIdx.x >> 3);
  const int mBlk = bid / 12, nBlk = bid % 12;
  const int m0 = mBlk * 256, n0 = nBlk * 256;

  // staging source pointers (global chunk pre-swizzled; LDS dest linear)
  const int rl = t >> 3;                       // 0..63
  const int cw = ((t & 7) ^ (rl & 7)) * 8;     // swizzled source chunk (halfwords)
  const unsigned short* aS[4];
  const unsigned short* bS[4];
#pragma unroll
  for (int h = 0; h < 4; ++h) {
    aS[h] = xb + (size_t)(m0 + h * 64 + rl) * K_ + cw;
    bS[h] = wb + (size_t)(n0 + h * 64 + rl) * K_ + cw;
  }

  const int aBase = (wr * 128 + lr) * 64;
  const int bBase = 16384 + (wc * 64 + lr) * 64;
  int chs[2];
#pragma unroll
  for (int s = 0; s < 2; ++s) chs[s] = ((s * 4 + lq) ^ (lr & 7)) * 8;

  f32x4 acc[8][4] = {};

  STAGE_T(0, 0);
  asm volatile("s_waitcnt vmcnt(0)" ::: "memory");
  __builtin_amdgcn_s_barrier();

  for (int u = 0; u < 16; ++u) {
    const int cur = u & 1;
    const unsigned short* Lc = &lds[cur][0];
    if (u + 1 < 16) STAGE_T(cur ^ 1, u + 1);   // issue next-tile loads FIRST

    bf16x8 afr[8][2], bfr[4][2];
#pragma unroll
    for (int mf = 0; mf < 8; ++mf)
#pragma unroll
      for (int s = 0; s < 2; ++s)
        afr[mf][s] = *(const bf16x8*)(Lc + aBase + mf * 1024 + chs[s]);
#pragma unroll
    for (int j = 0; j < 4; ++j)
#pragma unroll
      for (int s = 0; s < 2; ++s)
        bfr[j][s] = *(const bf16x8*)(Lc + bBase + j * 1024 + chs[s]);

#pragma unroll
    for (int mf = 0; mf < 8; ++mf)
#pragma unroll
      for (int j = 0; j < 4; ++j)
#pragma unroll
        for (int s = 0; s < 2; ++s)
          acc[mf][j] = MFMA16(afr[mf][s], bfr[j][s], acc[mf][j]);

    asm volatile("s_waitcnt vmcnt(0)\n\ts_barrier" ::: "memory");
  }

  // ---- fused epilogue ----
  if (n0 >= 2048) {
    // V blocks: bias only, u16x4 stores along n (= m)
#pragma unroll
    for (int mf = 0; mf < 8; ++mf) {
#pragma unroll
      for (int j = 0; j < 4; ++j) {
        const int ncol = n0 + wc * 64 + j * 16 + lr;
        const int hh = (ncol & 1023) >> 6;
        const int d = j * 16 + lr;
        const float bias_v = bias[ncol];
        const int m = m0 + wr * 128 + mf * 16 + lq * 4;  // base of 4 consecutive
        const int bb = m >> 9, nB = m & 511;
        u16x4 vv;
#pragma unroll
        for (int r = 0; r < 4; ++r) vv[r] = f2bf(acc[mf][j][r] + bias_v);
        *(u16x4*)(Vtb + ((size_t)(bb * H_ + hh) * D_ + d) * N_ + nB) = vv;
      }
    }
  } else {
    // Q/K blocks: elu+1, rope (Q also *1/8); interleaved float2 table loads
    const bool isQ = (n0 < 1024);
#pragma unroll
    for (int mf = 0; mf < 8; ++mf) {
#pragma unroll
      for (int j = 0; j < 4; ++j) {
        const int ncol = n0 + wc * 64 + j * 16 + lr;
        const int hh = (ncol & 1023) >> 6;
        const int d = ncol & 63;
        const float bias_v = bias[ncol];
        const int ip = d >> 1;
#pragma unroll
        for (int r = 0; r < 4; ++r) {
          const int m = m0 + wr * 128 + mf * 16 + lq * 4 + r;
          const int bb = m >> 9, n = m & 511;
          const float val = acc[mf][j][r] + bias_v;
          const float e = val > 0.f ? val + 1.f : expf(val);  // elu+1
          const float partner = __shfl_xor(e, 1);
          const float2 sc = sc_t[n * 32 + ip];
          float o = (d & 1) ? (partner * sc.x + e * sc.y) : (e * sc.y - partner * sc.x);
          if (isQ) o *= 0.125f;  // fold 1/sqrt(D) into Q
          unsigned short* dst = isQ ? Qb : Kb;
          dst[((size_t)(bb * H_ + hh) * N_ + n) * D_ + d] = f2bf(o);
        }
      }
    }
  }
}

// ---------- attention + lepe : persistent block, 2 bh per block ----------
// grid 256; block does bh = 2*bid + {0,1}. Cross-bh pipeline via region deadness:
//  - Ks dead after all waves' p=3 S-loop -> barrier + stage K(bh2) (lands under
//    p3 softmax/PV/lepe)
//  - Vs dead after p-loop -> barrier + stage V(bh2) + vmcnt(8) (K2+stores drained,
//    V2 in flight, hidden under bh2's QK^T; p==0 syncthreads drains before PV)
__global__ __launch_bounds__(512, 2) void attn_kernel(
    const unsigned short* __restrict__ Qb, const unsigned short* __restrict__ Kb,
    const unsigned short* __restrict__ Vtb,
    const float* __restrict__ w_lepe, const float* __restrict__ b_lepe,
    float* __restrict__ out) {
  __shared__ unsigned short Ks[512 * 64];      // 64 KB
  __shared__ unsigned short Vs[64 * 512];      // 64 KB
  __shared__ unsigned short Pb[8 * 2 * 1024];  // 32 KB
  const int t = threadIdx.x, wv = t >> 6, l = t & 63;
  const int lq = l >> 4, lr = l & 15;
  const int bid = blockIdx.x;          // 0..255

#define STAGE_K(gbase)                                                     \
  do {                                                                     \
    const int row8_ = t >> 3, ch_ = t & 7;                                 \
    _Pragma("unroll") for (int c_ = 0; c_ < 8; ++c_) {                     \
      const int r_ = c_ * 64 + row8_;                                      \
      const int sch_ = ch_ ^ (r_ & 7);                                     \
      glds16(Kb + (gbase) + (size_t)r_ * D_ + sch_ * 8,                    \
             Ks + c_ * 4096 + t * 8);                                      \
    }                                                                      \
  } while (0)
#define STAGE_V(gbase)                                                     \
  do {                                                                     \
    const int ch_ = t & 63;                                                \
    _Pragma("unroll") for (int c_ = 0; c_ < 8; ++c_) {                     \
      const int d_ = c_ * 8 + wv;                                          \
      const int sch_ = ch_ ^ (d_ & 7);                                     \
      glds16(Vtb + (gbase) + (size_t)d_ * N_ + sch_ * 8,                   \
             Vs + c_ * 4096 + t * 8);                                      \
    }                                                                      \
  } while (0)

  // initial staging for bh0
  STAGE_K((size_t)(bid * 2) * (N_ * D_));
  STAGE_V((size_t)(bid * 2) * (N_ * D_));
  asm volatile("s_waitcnt vmcnt(8)" ::: "memory");
  __builtin_amdgcn_s_barrier();

  unsigned short* PwA = Pb + wv * 2048;  // buf0 [16 q][64 k], 16B-slot swizzle
  unsigned short* PwB = PwA + 1024;      // buf1

#define PWRITE(ccv, Pdst)                                                        \
  do {                                                                           \
    _Pragma("unroll") for (int kl = 0; kl < 4; ++kl) {                           \
      const int kt_ = (ccv) * 4 + kl;                                            \
      u16x4 pk;                                                                  \
      _Pragma("unroll") for (int r = 0; r < 4; ++r) pk[r] = f2bf(s[kt_][r] * inv); \
      const int slot = kl * 2 + (lq >> 1);                                       \
      *(u16x4*)((Pdst) + lr * 64 + ((slot ^ (lr & 7)) << 3) + (lq & 1) * 4) = pk; \
    }                                                                            \
  } while (0)

  for (int bhi = 0; bhi < 2; ++bhi) {
    const int bh = bid * 2 + bhi;
    const int bb = bh >> 4, h = bh & 15;
    const size_t base = (size_t)bh * (N_ * D_);
    const size_t base2 = base + (size_t)(N_ * D_);  // next bh (used when bhi==0)

    // Q for p=0 of this bh
    bf16x8 qf0 = *(const bf16x8*)(Qb + base + (size_t)(wv * 64 + lr) * D_ + lq * 8);
    bf16x8 qf1 = *(const bf16x8*)(Qb + base + (size_t)(wv * 64 + lr) * D_ + 32 + lq * 8);

    for (int p = 0; p < 4; ++p) {
      const int ql = wv * 64 + p * 16;

      // S^T via swapped mfma(K,Q): s[kt][r] = S[q=ql+lr][k=kt*16+lq*4+r]
      f32x4 s[32];
#pragma unroll
      for (int kt = 0; kt < 32; ++kt) {
        const int r = kt * 16 + lr;
        const int rx = r & 7;
        const unsigned short* kr = Ks + r * 64;
        const bf16x8 kf0 = *(const bf16x8*)(kr + (lq ^ rx) * 8);
        const bf16x8 kf1 = *(const bf16x8*)(kr + ((lq + 4) ^ rx) * 8);
        f32x4 a = {0.f, 0.f, 0.f, 0.f};
        a = MFMA16(kf0, qf0, a);
        a = MFMA16(kf1, qf1, a);
        s[kt] = a;
      }

      // Ks dead block-wide after every wave's p=3 S-loop: stage next bh's K
      if (p == 3 && bhi == 0) {
        __syncthreads();
        STAGE_K(base2);
      }

      // prefetch next p's Q (hides L2 latency under softmax+PV)
      if (p < 3) {
        const int qn = ql + 16;
        qf0 = *(const bf16x8*)(Qb + base + (size_t)(qn + lr) * D_ + lq * 8);
        qf1 = *(const bf16x8*)(Qb + base + (size_t)(qn + lr) * D_ + 32 + lq * 8);
      }

      // softmax for row q=ql+lr: 8 parallel accumulator chains, then combine
      float macc[8];
#pragma unroll
      for (int i = 0; i < 8; ++i) macc[i] = -1e30f;
#pragma unroll
      for (int kt = 0; kt < 32; ++kt)
#pragma unroll
        for (int r = 0; r < 4; ++r)
          macc[(kt & 1) * 4 + r] = fmaxf(macc[(kt & 1) * 4 + r], s[kt][r]);
#pragma unroll
      for (int i = 0; i < 4; ++i) macc[i] = fmaxf(macc[i], macc[i + 4]);
      macc[0] = fmaxf(macc[0], macc[1]);
      macc[2] = fmaxf(macc[2], macc[3]);
      float m = fmaxf(macc[0], macc[2]);
      m = fmaxf(m, __shfl_xor(m, 16));
      m = fmaxf(m, __shfl_xor(m, 32));

      float sacc[8];
#pragma unroll
      for (int i = 0; i < 8; ++i) sacc[i] = 0.f;
#pragma unroll
      for (int kt = 0; kt < 32; ++kt)
#pragma unroll
        for (int r = 0; r < 4; ++r) {
          const float pv = __expf(s[kt][r] - m);   // scale pre-folded into Q
          s[kt][r] = pv;
          sacc[(kt & 1) * 4 + r] += pv;
        }
#pragma unroll
      for (int i = 0; i < 4; ++i) sacc[i] += sacc[i + 4];
      sacc[0] += sacc[1];
      sacc[2] += sacc[3];
      float su = sacc[0] + sacc[2];
      su += __shfl_xor(su, 16);
      su += __shfl_xor(su, 32);
      const float inv = 1.0f / su;

      if (p == 0) __syncthreads();  // V staged (barrier drains vmcnt); uniform

      // PV: 8 chunks of 64 k through double-buffered P; counted RAW wait only.
      f32x4 o[4] = {};
      PWRITE(0, PwA);
#pragma unroll
      for (int cc = 0; cc < 8; ++cc) {
        unsigned short* bufC = (cc & 1) ? PwB : PwA;
        unsigned short* bufN = (cc & 1) ? PwA : PwB;
        if (cc < 7) PWRITE(cc + 1, bufN);
        // in-order DS queue: <=4 outstanding == next chunk's writes => cc's retired
        asm volatile("s_waitcnt lgkmcnt(4)" ::: "memory");
#pragma unroll
        for (int w = 0; w < 2; ++w) {
          const u16x8 pr =
              *(const u16x8*)(bufC + lr * 64 + (((w * 4 + lq) ^ (lr & 7)) << 3));
          const bf16x8 pf = as_bf16x8(pr);
          const int ci = cc * 8 + w * 4 + lq;
#pragma unroll
          for (int j2 = 0; j2 < 4; j2++) {
            const int dr = j2 * 16 + lr;
            const bf16x8 vf = *(const bf16x8*)(Vs + dr * 512 + ((ci ^ (dr & 7)) << 3));
            o[j2] = MFMA16(pf, vf, o[j2]);
          }
        }
      }

      // epilogue: + lepe (depthwise conv3 over n from resident Vs); write fp32
#pragma unroll
      for (int j2 = 0; j2 < 4; j2++) {
        const int d = j2 * 16 + lr;
        const int c = h * 64 + d;
        const float w0 = w_lepe[c * 3 + 0], w1 = w_lepe[c * 3 + 1],
                    w2 = w_lepe[c * 3 + 2];
        const float bl = b_lepe[c];
        const int dx = d & 7;
#pragma unroll
        for (int r = 0; r < 4; r++) {
          const int n = ql + lq * 4 + r;
          float vm1 = 0.f, vp1 = 0.f;
          if (n > 0) {
            const int nn = n - 1;
            vm1 = bf2f(Vs[d * 512 + (((nn >> 3) ^ dx) << 3) + (nn & 7)]);
          }
          const float v0 = bf2f(Vs[d * 512 + (((n >> 3) ^ dx) << 3) + (n & 7)]);
          if (n < 511) {
            const int nn = n + 1;
            vp1 = bf2f(Vs[d * 512 + (((nn >> 3) ^ dx) << 3) + (nn & 7)]);
          }
          const float lepe = vm1 * w0 + v0 * w1 + vp1 * w2 + bl;
          out[((size_t)(bb * N_ + n)) * C_ + c] = o[j2][r] + lepe;
        }
      }
    }

    // Vs dead: stage next bh's V; K2 + out-stores drained, V2 rides under QK^T
    if (bhi == 0) {
      __syncthreads();
      STAGE_V(base2);
      asm volatile("s_waitcnt vmcnt(8)" ::: "memory");
      __builtin_amdgcn_s_barrier();
    }
  }
#undef PWRITE
#undef STAGE_K
#undef STAGE_V
}

// ---------- launcher ----------
extern "C" void kernel_launch(void* const* d_in, const int* in_sizes, int n_in,
                              void* d_out, int out_size, void* d_ws, size_t ws_size,
                              hipStream_t stream) {
  (void)in_sizes; (void)n_in; (void)out_size; (void)ws_size;
  const float* x = (const float*)d_in[0];
  const float* w_qkv = (const float*)d_in[1];
  const float* b_qkv = (const float*)d_in[2];
  const float* w_lepe = (const float*)d_in[3];
  const float* b_lepe = (const float*)d_in[4];
  float* out = (float*)d_out;

  unsigned short* ws = (unsigned short*)d_ws;
  unsigned short* xb = ws;                          // 16777216 el
  unsigned short* wb = xb + 16777216;               // 3145728 el
  unsigned short* Qb = wb + 3145728;                // 16777216 el
  unsigned short* Kb = Qb + 16777216;               // 16777216 el
  unsigned short* Vtb = Kb + 16777216;              // 16777216 el
  float2* sc_t = (float2*)(Vtb + 16777216);         // 16384 float2

  const int prep_units = NX8 + NW8 + NT8;           // 2,492,416
  prep_kernel<<<(prep_units + 255) / 256, 256, 0, stream>>>(x, w_qkv, xb, wb, sc_t);
  qkv_gemm_kernel<<<768, 512, 0, stream>>>(xb, wb, b_qkv, Qb, Kb, Vtb, sc_t);
  attn_kernel<<<256, 512, 0, stream>>>(Qb, Kb, Vtb, w_lepe, b_lepe, out);
}

// Round 19
// 234.969 us; speedup vs baseline: 1.0051x; 1.0051x over previous
//
#include <hip/hip_runtime.h>
#include <stdint.h>

// ---------- types ----------
typedef __attribute__((ext_vector_type(8))) __bf16 bf16x8;
typedef __attribute__((ext_vector_type(4))) float f32x4;
typedef __attribute__((ext_vector_type(8))) unsigned short u16x8;
typedef __attribute__((ext_vector_type(4))) unsigned short u16x4;

#define MFMA16(a, b, c) __builtin_amdgcn_mfma_f32_16x16x32_bf16((a), (b), (c), 0, 0, 0)

__device__ __forceinline__ void glds16(const void* g, void* l) {
  __builtin_amdgcn_global_load_lds(
      (const __attribute__((address_space(1))) void*)(uintptr_t)g,
      (__attribute__((address_space(3))) void*)(uint32_t)(uintptr_t)l,
      16, 0, 0);
}

__device__ __forceinline__ unsigned short f2bf(float f) {
  union { float f; unsigned u; } v; v.f = f;
  unsigned r = v.u + 0x7FFFu + ((v.u >> 16) & 1u);
  return (unsigned short)(r >> 16);
}
__device__ __forceinline__ float bf2f(unsigned short s) {
  union { unsigned u; float f; } v; v.u = ((unsigned)s) << 16;
  return v.f;
}
__device__ __forceinline__ bf16x8 as_bf16x8(u16x8 v) {
  union { u16x8 u; bf16x8 b; } c; c.u = v; return c.b;
}

// ---------- problem constants ----------
#define B_ 32
#define N_ 512
#define C_ 1024
#define H_ 16
#define D_ 64
#define K_ C_                // 1024

#define NX8 2097152          // x elements / 8
#define NW8 393216           // w elements / 8
#define NT8 2048             // table entries / 8

// ---------- fused prep: x->bf16 | w->bf16 | rope float2 table, one launch ----------
__global__ __launch_bounds__(256) void prep_kernel(
    const float* __restrict__ x, const float* __restrict__ w,
    unsigned short* __restrict__ xb, unsigned short* __restrict__ wb,
    float2* __restrict__ sc_t) {
  const int i = blockIdx.x * 256 + threadIdx.x;
  if (i < NX8 + NW8) {
    const float* src = (i < NX8) ? x : w;
    unsigned short* dst = (i < NX8) ? xb : wb;
    const int k = (i < NX8) ? i : i - NX8;
    const float4* p = reinterpret_cast<const float4*>(src) + (size_t)k * 2;
    float4 a = p[0], b = p[1];
    u16x8 o;
    o[0] = f2bf(a.x); o[1] = f2bf(a.y); o[2] = f2bf(a.z); o[3] = f2bf(a.w);
    o[4] = f2bf(b.x); o[5] = f2bf(b.y); o[6] = f2bf(b.z); o[7] = f2bf(b.w);
    *reinterpret_cast<u16x8*>(dst + (size_t)k * 8) = o;
  } else if (i < NX8 + NW8 + NT8) {
    const int base = (i - NX8 - NW8) * 8;
#pragma unroll
    for (int e = 0; e < 8; ++e) {
      const int idx = base + e;           // n*32 + ip
      const int n = idx >> 5, ip = idx & 31;
      const float div = expf(-(2.0f * (float)ip) * (9.210340371976184f / 64.0f));
      const float ang = (float)n * div;
      sc_t[idx] = make_float2(sinf(ang), cosf(ang));
    }
  }
}

// ---------- QKV GEMM: 256x256, BK=64, minimum 2-phase ----------
#define STAGE_T(bi, uu)                                                \
  do {                                                                 \
    _Pragma("unroll") for (int h_ = 0; h_ < 4; ++h_) {                 \
      glds16(aS[h_] + (size_t)(uu) * 64, &lds[bi][h_ * 4096 + t * 8]); \
      glds16(bS[h_] + (size_t)(uu) * 64,                               \
             &lds[bi][16384 + h_ * 4096 + t * 8]);                     \
    }                                                                  \
  } while (0)

__global__ __launch_bounds__(512, 2) void qkv_gemm_kernel(
    const unsigned short* __restrict__ xb, const unsigned short* __restrict__ wb,
    const float* __restrict__ bias,
    unsigned short* __restrict__ Qb, unsigned short* __restrict__ Kb,
    unsigned short* __restrict__ Vtb,
    const float2* __restrict__ sc_t) {
  __shared__ unsigned short lds[2][32768];  // 128 KB
  const int t = threadIdx.x;
  const int wv = t >> 6, l = t & 63;
  const int wr = wv >> 2, wc = wv & 3;   // 2 x 4 waves, wave tile 128x64
  const int lq = l >> 4, lr = l & 15;

  // XCD-chunked bijective swizzle (768 = 8 * 96)
  const int bid = (blockIdx.x & 7) * 96 + (blockIdx.x >> 3);
  const int mBlk = bid / 12, nBlk = bid % 12;
  const int m0 = mBlk * 256, n0 = nBlk * 256;

  // staging source pointers (global chunk pre-swizzled; LDS dest linear)
  const int rl = t >> 3;                       // 0..63
  const int cw = ((t & 7) ^ (rl & 7)) * 8;     // swizzled source chunk (halfwords)
  const unsigned short* aS[4];
  const unsigned short* bS[4];
#pragma unroll
  for (int h = 0; h < 4; ++h) {
    aS[h] = xb + (size_t)(m0 + h * 64 + rl) * K_ + cw;
    bS[h] = wb + (size_t)(n0 + h * 64 + rl) * K_ + cw;
  }

  const int aBase = (wr * 128 + lr) * 64;
  const int bBase = 16384 + (wc * 64 + lr) * 64;
  int chs[2];
#pragma unroll
  for (int s = 0; s < 2; ++s) chs[s] = ((s * 4 + lq) ^ (lr & 7)) * 8;

  f32x4 acc[8][4] = {};

  STAGE_T(0, 0);
  asm volatile("s_waitcnt vmcnt(0)" ::: "memory");
  __builtin_amdgcn_s_barrier();

  for (int u = 0; u < 16; ++u) {
    const int cur = u & 1;
    const unsigned short* Lc = &lds[cur][0];
    if (u + 1 < 16) STAGE_T(cur ^ 1, u + 1);   // issue next-tile loads FIRST

    bf16x8 afr[8][2], bfr[4][2];
#pragma unroll
    for (int mf = 0; mf < 8; ++mf)
#pragma unroll
      for (int s = 0; s < 2; ++s)
        afr[mf][s] = *(const bf16x8*)(Lc + aBase + mf * 1024 + chs[s]);
#pragma unroll
    for (int j = 0; j < 4; ++j)
#pragma unroll
      for (int s = 0; s < 2; ++s)
        bfr[j][s] = *(const bf16x8*)(Lc + bBase + j * 1024 + chs[s]);

#pragma unroll
    for (int mf = 0; mf < 8; ++mf)
#pragma unroll
      for (int j = 0; j < 4; ++j)
#pragma unroll
        for (int s = 0; s < 2; ++s)
          acc[mf][j] = MFMA16(afr[mf][s], bfr[j][s], acc[mf][j]);

    asm volatile("s_waitcnt vmcnt(0)\n\ts_barrier" ::: "memory");
  }

  // ---- fused epilogue ----
  if (n0 >= 2048) {
    // V blocks: bias only, u16x4 stores along n (= m)
#pragma unroll
    for (int mf = 0; mf < 8; ++mf) {
#pragma unroll
      for (int j = 0; j < 4; ++j) {
        const int ncol = n0 + wc * 64 + j * 16 + lr;
        const int hh = (ncol & 1023) >> 6;
        const int d = j * 16 + lr;
        const float bias_v = bias[ncol];
        const int m = m0 + wr * 128 + mf * 16 + lq * 4;  // base of 4 consecutive
        const int bb = m >> 9, nB = m & 511;
        u16x4 vv;
#pragma unroll
        for (int r = 0; r < 4; ++r) vv[r] = f2bf(acc[mf][j][r] + bias_v);
        *(u16x4*)(Vtb + ((size_t)(bb * H_ + hh) * D_ + d) * N_ + nB) = vv;
      }
    }
  } else {
    // Q/K blocks: elu+1, rope (Q also *1/8); interleaved float2 table loads
    const bool isQ = (n0 < 1024);
#pragma unroll
    for (int mf = 0; mf < 8; ++mf) {
#pragma unroll
      for (int j = 0; j < 4; ++j) {
        const int ncol = n0 + wc * 64 + j * 16 + lr;
        const int hh = (ncol & 1023) >> 6;
        const int d = ncol & 63;
        const float bias_v = bias[ncol];
        const int ip = d >> 1;
#pragma unroll
        for (int r = 0; r < 4; ++r) {
          const int m = m0 + wr * 128 + mf * 16 + lq * 4 + r;
          const int bb = m >> 9, n = m & 511;
          const float val = acc[mf][j][r] + bias_v;
          const float e = val > 0.f ? val + 1.f : expf(val);  // elu+1
          const float partner = __shfl_xor(e, 1);
          const float2 sc = sc_t[n * 32 + ip];
          float o = (d & 1) ? (partner * sc.x + e * sc.y) : (e * sc.y - partner * sc.x);
          if (isQ) o *= 0.125f;  // fold 1/sqrt(D) into Q
          unsigned short* dst = isQ ? Qb : Kb;
          dst[((size_t)(bb * H_ + hh) * N_ + n) * D_ + d] = f2bf(o);
        }
      }
    }
  }
}

// ---------- attention + lepe : one block per (b,h) (R17 best-known) ----------
__global__ __launch_bounds__(512, 2) void attn_kernel(
    const unsigned short* __restrict__ Qb, const unsigned short* __restrict__ Kb,
    const unsigned short* __restrict__ Vtb,
    const float* __restrict__ w_lepe, const float* __restrict__ b_lepe,
    float* __restrict__ out) {
  __shared__ unsigned short Ks[512 * 64];      // 64 KB
  __shared__ unsigned short Vs[64 * 512];      // 64 KB
  __shared__ unsigned short Pb[8 * 2 * 1024];  // 32 KB: per wave 2 bufs x [16][64]
  const int t = threadIdx.x, wv = t >> 6, l = t & 63;
  const int lq = l >> 4, lr = l & 15;
  const int bh = blockIdx.x;           // 0..511
  const int bb = bh >> 4, h = bh & 15;
  const size_t base = (size_t)bh * (N_ * D_);

  {
    const int row8 = t >> 3, ch = t & 7;
#pragma unroll
    for (int c = 0; c < 8; ++c) {
      const int r = c * 64 + row8;
      const int sch = ch ^ (r & 7);
      glds16(Kb + base + (size_t)r * D_ + sch * 8, Ks + c * 4096 + t * 8);
    }
  }
  {
    const int ch = t & 63;
#pragma unroll
    for (int c = 0; c < 8; ++c) {
      const int d = c * 8 + wv;
      const int sch = ch ^ (d & 7);
      glds16(Vtb + base + (size_t)d * N_ + sch * 8, Vs + c * 4096 + t * 8);
    }
  }

  asm volatile("s_waitcnt vmcnt(8)" ::: "memory");
  __builtin_amdgcn_s_barrier();

  unsigned short* PwA = Pb + wv * 2048;  // buf0 [16 q][64 k], 16B-slot swizzle
  unsigned short* PwB = PwA + 1024;      // buf1

#define PWRITE(ccv, Pdst)                                                        \
  do {                                                                           \
    _Pragma("unroll") for (int kl = 0; kl < 4; ++kl) {                           \
      const int kt_ = (ccv) * 4 + kl;                                            \
      u16x4 pk;                                                                  \
      _Pragma("unroll") for (int r = 0; r < 4; ++r) pk[r] = f2bf(s[kt_][r] * inv); \
      const int slot = kl * 2 + (lq >> 1);                                       \
      *(u16x4*)((Pdst) + lr * 64 + ((slot ^ (lr & 7)) << 3) + (lq & 1) * 4) = pk; \
    }                                                                            \
  } while (0)

  // Q prefetch: load p=0 before the loop; issue p+1 right after the S-loop
  bf16x8 qf0 = *(const bf16x8*)(Qb + base + (size_t)(wv * 64 + lr) * D_ + lq * 8);
  bf16x8 qf1 = *(const bf16x8*)(Qb + base + (size_t)(wv * 64 + lr) * D_ + 32 + lq * 8);

  for (int p = 0; p < 4; ++p) {
    const int ql = wv * 64 + p * 16;

    // S^T via swapped mfma(K,Q): s[kt][r] = S[q=ql+lr][k=kt*16+lq*4+r]
    f32x4 s[32];
#pragma unroll
    for (int kt = 0; kt < 32; ++kt) {
      const int r = kt * 16 + lr;
      const int rx = r & 7;
      const unsigned short* kr = Ks + r * 64;
      const bf16x8 kf0 = *(const bf16x8*)(kr + (lq ^ rx) * 8);
      const bf16x8 kf1 = *(const bf16x8*)(kr + ((lq + 4) ^ rx) * 8);
      f32x4 a = {0.f, 0.f, 0.f, 0.f};
      a = MFMA16(kf0, qf0, a);
      a = MFMA16(kf1, qf1, a);
      s[kt] = a;
    }

    // prefetch next p's Q (hides L2 latency under softmax+PV)
    if (p < 3) {
      const int qn = ql + 16;
      qf0 = *(const bf16x8*)(Qb + base + (size_t)(qn + lr) * D_ + lq * 8);
      qf1 = *(const bf16x8*)(Qb + base + (size_t)(qn + lr) * D_ + 32 + lq * 8);
    }

    // softmax for row q=ql+lr: 8 parallel accumulator chains, then combine
    float macc[8];
#pragma unroll
    for (int i = 0; i < 8; ++i) macc[i] = -1e30f;
#pragma unroll
    for (int kt = 0; kt < 32; ++kt)
#pragma unroll
      for (int r = 0; r < 4; ++r)
        macc[(kt & 1) * 4 + r] = fmaxf(macc[(kt & 1) * 4 + r], s[kt][r]);
#pragma unroll
    for (int i = 0; i < 4; ++i) macc[i] = fmaxf(macc[i], macc[i + 4]);
    macc[0] = fmaxf(macc[0], macc[1]);
    macc[2] = fmaxf(macc[2], macc[3]);
    float m = fmaxf(macc[0], macc[2]);
    m = fmaxf(m, __shfl_xor(m, 16));
    m = fmaxf(m, __shfl_xor(m, 32));

    float sacc[8];
#pragma unroll
    for (int i = 0; i < 8; ++i) sacc[i] = 0.f;
#pragma unroll
    for (int kt = 0; kt < 32; ++kt)
#pragma unroll
      for (int r = 0; r < 4; ++r) {
        const float pv = __expf(s[kt][r] - m);   // scale pre-folded into Q
        s[kt][r] = pv;
        sacc[(kt & 1) * 4 + r] += pv;
      }
#pragma unroll
    for (int i = 0; i < 4; ++i) sacc[i] += sacc[i + 4];
    sacc[0] += sacc[1];
    sacc[2] += sacc[3];
    float su = sacc[0] + sacc[2];
    su += __shfl_xor(su, 16);
    su += __shfl_xor(su, 32);
    const float inv = 1.0f / su;

    if (p == 0) __syncthreads();  // V staged (drains vmcnt); all waves reach once

    // PV: 8 chunks of 64 k through double-buffered P; counted RAW wait only.
    f32x4 o[4] = {};
    PWRITE(0, PwA);
#pragma unroll
    for (int cc = 0; cc < 8; ++cc) {
      unsigned short* bufC = (cc & 1) ? PwB : PwA;
      unsigned short* bufN = (cc & 1) ? PwA : PwB;
      if (cc < 7) PWRITE(cc + 1, bufN);
      // in-order DS queue: <=4 outstanding == next chunk's writes => cc's retired
      asm volatile("s_waitcnt lgkmcnt(4)" ::: "memory");
#pragma unroll
      for (int w = 0; w < 2; ++w) {
        const u16x8 pr =
            *(const u16x8*)(bufC + lr * 64 + (((w * 4 + lq) ^ (lr & 7)) << 3));
        const bf16x8 pf = as_bf16x8(pr);
        const int ci = cc * 8 + w * 4 + lq;
#pragma unroll
        for (int j2 = 0; j2 < 4; j2++) {
          const int dr = j2 * 16 + lr;
          const bf16x8 vf = *(const bf16x8*)(Vs + dr * 512 + ((ci ^ (dr & 7)) << 3));
          o[j2] = MFMA16(pf, vf, o[j2]);
        }
      }
    }

    // epilogue: + lepe (depthwise conv3 over n from resident Vs); write fp32
#pragma unroll
    for (int j2 = 0; j2 < 4; j2++) {
      const int d = j2 * 16 + lr;
      const int c = h * 64 + d;
      const float w0 = w_lepe[c * 3 + 0], w1 = w_lepe[c * 3 + 1], w2 = w_lepe[c * 3 + 2];
      const float bl = b_lepe[c];
      const int dx = d & 7;
#pragma unroll
      for (int r = 0; r < 4; r++) {
        const int n = ql + lq * 4 + r;
        float vm1 = 0.f, vp1 = 0.f;
        if (n > 0) {
          const int nn = n - 1;
          vm1 = bf2f(Vs[d * 512 + (((nn >> 3) ^ dx) << 3) + (nn & 7)]);
        }
        const float v0 = bf2f(Vs[d * 512 + (((n >> 3) ^ dx) << 3) + (n & 7)]);
        if (n < 511) {
          const int nn = n + 1;
          vp1 = bf2f(Vs[d * 512 + (((nn >> 3) ^ dx) << 3) + (nn & 7)]);
        }
        const float lepe = vm1 * w0 + v0 * w1 + vp1 * w2 + bl;
        out[((size_t)(bb * N_ + n)) * C_ + c] = o[j2][r] + lepe;
      }
    }
  }
#undef PWRITE
}

// ---------- launcher ----------
extern "C" void kernel_launch(void* const* d_in, const int* in_sizes, int n_in,
                              void* d_out, int out_size, void* d_ws, size_t ws_size,
                              hipStream_t stream) {
  (void)in_sizes; (void)n_in; (void)out_size; (void)ws_size;
  const float* x = (const float*)d_in[0];
  const float* w_qkv = (const float*)d_in[1];
  const float* b_qkv = (const float*)d_in[2];
  const float* w_lepe = (const float*)d_in[3];
  const float* b_lepe = (const float*)d_in[4];
  float* out = (float*)d_out;

  unsigned short* ws = (unsigned short*)d_ws;
  unsigned short* xb = ws;                          // 16777216 el
  unsigned short* wb = xb + 16777216;               // 3145728 el
  unsigned short* Qb = wb + 3145728;                // 16777216 el
  unsigned short* Kb = Qb + 16777216;               // 16777216 el
  unsigned short* Vtb = Kb + 16777216;              // 16777216 el
  float2* sc_t = (float2*)(Vtb + 16777216);         // 16384 float2

  const int prep_units = NX8 + NW8 + NT8;           // 2,492,416
  prep_kernel<<<(prep_units + 255) / 256, 256, 0, stream>>>(x, w_qkv, xb, wb, sc_t);
  qkv_gemm_kernel<<<768, 512, 0, stream>>>(xb, wb, b_qkv, Qb, Kb, Vtb, sc_t);
  attn_kernel<<<512, 512, 0, stream>>>(Qb, Kb, Vtb, w_lepe, b_lepe, out);
}

// Round 20
// 224.843 us; speedup vs baseline: 1.0504x; 1.0450x over previous
//
#include <hip/hip_runtime.h>
#include <stdint.h>

// ---------- types ----------
typedef __attribute__((ext_vector_type(8))) __bf16 bf16x8;
typedef __attribute__((ext_vector_type(4))) float f32x4;
typedef __attribute__((ext_vector_type(8))) unsigned short u16x8;
typedef __attribute__((ext_vector_type(4))) unsigned short u16x4;

#define MFMA16(a, b, c) __builtin_amdgcn_mfma_f32_16x16x32_bf16((a), (b), (c), 0, 0, 0)

__device__ __forceinline__ void glds16(const void* g, void* l) {
  __builtin_amdgcn_global_load_lds(
      (const __attribute__((address_space(1))) void*)(uintptr_t)g,
      (__attribute__((address_space(3))) void*)(uint32_t)(uintptr_t)l,
      16, 0, 0);
}

__device__ __forceinline__ unsigned short f2bf(float f) {
  union { float f; unsigned u; } v; v.f = f;
  unsigned r = v.u + 0x7FFFu + ((v.u >> 16) & 1u);
  return (unsigned short)(r >> 16);
}
__device__ __forceinline__ float bf2f(unsigned short s) {
  union { unsigned u; float f; } v; v.u = ((unsigned)s) << 16;
  return v.f;
}
__device__ __forceinline__ bf16x8 as_bf16x8(u16x8 v) {
  union { u16x8 u; bf16x8 b; } c; c.u = v; return c.b;
}

// ---------- problem constants ----------
#define B_ 32
#define N_ 512
#define C_ 1024
#define H_ 16
#define D_ 64
#define K_ C_                // 1024

#define NX8 2097152          // x elements / 8
#define NW8 393216           // w elements / 8
#define NT8 2048             // table entries / 8

// ---------- fused prep: x->bf16 | w->bf16 | rope float2 table, one launch ----------
__global__ __launch_bounds__(256) void prep_kernel(
    const float* __restrict__ x, const float* __restrict__ w,
    unsigned short* __restrict__ xb, unsigned short* __restrict__ wb,
    float2* __restrict__ sc_t) {
  const int i = blockIdx.x * 256 + threadIdx.x;
  if (i < NX8 + NW8) {
    const float* src = (i < NX8) ? x : w;
    unsigned short* dst = (i < NX8) ? xb : wb;
    const int k = (i < NX8) ? i : i - NX8;
    const float4* p = reinterpret_cast<const float4*>(src) + (size_t)k * 2;
    float4 a = p[0], b = p[1];
    u16x8 o;
    o[0] = f2bf(a.x); o[1] = f2bf(a.y); o[2] = f2bf(a.z); o[3] = f2bf(a.w);
    o[4] = f2bf(b.x); o[5] = f2bf(b.y); o[6] = f2bf(b.z); o[7] = f2bf(b.w);
    *reinterpret_cast<u16x8*>(dst + (size_t)k * 8) = o;
  } else if (i < NX8 + NW8 + NT8) {
    const int base = (i - NX8 - NW8) * 8;
#pragma unroll
    for (int e = 0; e < 8; ++e) {
      const int idx = base + e;           // n*32 + ip
      const int n = idx >> 5, ip = idx & 31;
      const float div = expf(-(2.0f * (float)ip) * (9.210340371976184f / 64.0f));
      const float ang = (float)n * div;
      sc_t[idx] = make_float2(sinf(ang), cosf(ang));
    }
  }
}

// ---------- QKV GEMM: 256x256, BK=64; A-triple/B-double buffers, counted vmcnt ----------
// LDS layout (halfwords): A bufs at 0/16384/32768, B bufs at 49152/65536 = 160KB.
// Body u: vmcnt(4) [B(u) youngest needed; A(u+1) stays in flight] -> barrier ->
// issue B(u+1)->Bbuf[(u+1)&1], A(u+2)->Abuf[(u+2)%3] -> ds_read -> 64 MFMA.
// No vmcnt(0) in the loop: A gets 2 bodies to land, B one body.
// WAR: staged regions' readers retired before this body's barrier (ds_read ->
// MFMA program order); RAW: the counted wait + barrier.
#define STAGE_A(dstoff, uu)                                            \
  do {                                                                 \
    _Pragma("unroll") for (int h_ = 0; h_ < 4; ++h_)                   \
      glds16(aS[h_] + (size_t)(uu) * 64,                               \
             &lds[(dstoff) + h_ * 4096 + t * 8]);                      \
  } while (0)
#define STAGE_B(dstoff, uu)                                            \
  do {                                                                 \
    _Pragma("unroll") for (int h_ = 0; h_ < 4; ++h_)                   \
      glds16(bS[h_] + (size_t)(uu) * 64,                               \
             &lds[(dstoff) + h_ * 4096 + t * 8]);                      \
  } while (0)

__global__ __launch_bounds__(512, 2) void qkv_gemm_kernel(
    const unsigned short* __restrict__ xb, const unsigned short* __restrict__ wb,
    const float* __restrict__ bias,
    unsigned short* __restrict__ Qb, unsigned short* __restrict__ Kb,
    unsigned short* __restrict__ Vtb,
    const float2* __restrict__ sc_t) {
  __shared__ unsigned short lds[81920];  // 160 KB
  const int t = threadIdx.x;
  const int wv = t >> 6, l = t & 63;
  const int wr = wv >> 2, wc = wv & 3;   // 2 x 4 waves, wave tile 128x64
  const int lq = l >> 4, lr = l & 15;

  // XCD-chunked bijective swizzle (768 = 8 * 96)
  const int bid = (blockIdx.x & 7) * 96 + (blockIdx.x >> 3);
  const int mBlk = bid / 12, nBlk = bid % 12;
  const int m0 = mBlk * 256, n0 = nBlk * 256;

  // staging source pointers (global chunk pre-swizzled; LDS dest linear)
  const int rl = t >> 3;                       // 0..63
  const int cw = ((t & 7) ^ (rl & 7)) * 8;     // swizzled source chunk (halfwords)
  const unsigned short* aS[4];
  const unsigned short* bS[4];
#pragma unroll
  for (int h = 0; h < 4; ++h) {
    aS[h] = xb + (size_t)(m0 + h * 64 + rl) * K_ + cw;
    bS[h] = wb + (size_t)(n0 + h * 64 + rl) * K_ + cw;
  }

  // fragment read offsets within a buffer (halfwords)
  const int aBase = (wr * 128 + lr) * 64;
  const int bBase = (wc * 64 + lr) * 64;
  int chs[2];
#pragma unroll
  for (int s = 0; s < 2; ++s) chs[s] = ((s * 4 + lq) ^ (lr & 7)) * 8;

  f32x4 acc[8][4] = {};

  // prologue: A(0), B(0), A(1)  [issue order = age order]
  STAGE_A(0, 0);
  STAGE_B(49152, 0);
  STAGE_A(16384, 1);

  // rotating buffer offsets (halfwords); explicit rotation, no runtime modulo
  int aCur = 0, aNx1 = 16384, aNx2 = 32768;
  int bCur = 49152, bNxt = 65536;

  for (int u = 0; u < 16; ++u) {
    if (u == 15) asm volatile("s_waitcnt vmcnt(0)" ::: "memory");
    else         asm volatile("s_waitcnt vmcnt(4)" ::: "memory");
    __builtin_amdgcn_s_barrier();

    // stage ahead: B first (youngest-needed discipline), then A
    if (u + 1 < 16) STAGE_B(bNxt, u + 1);
    if (u + 2 < 16) STAGE_A(aNx2, u + 2);

    const unsigned short* La = &lds[aCur];
    const unsigned short* Lb = &lds[bCur];
    bf16x8 afr[8][2], bfr[4][2];
#pragma unroll
    for (int mf = 0; mf < 8; ++mf)
#pragma unroll
      for (int s = 0; s < 2; ++s)
        afr[mf][s] = *(const bf16x8*)(La + aBase + mf * 1024 + chs[s]);
#pragma unroll
    for (int j = 0; j < 4; ++j)
#pragma unroll
      for (int s = 0; s < 2; ++s)
        bfr[j][s] = *(const bf16x8*)(Lb + bBase + j * 1024 + chs[s]);

#pragma unroll
    for (int mf = 0; mf < 8; ++mf)
#pragma unroll
      for (int j = 0; j < 4; ++j)
#pragma unroll
        for (int s = 0; s < 2; ++s)
          acc[mf][j] = MFMA16(afr[mf][s], bfr[j][s], acc[mf][j]);

    // rotate buffers
    const int aOld = aCur;
    aCur = aNx1; aNx1 = aNx2; aNx2 = aOld;
    const int bOld = bCur;
    bCur = bNxt; bNxt = bOld;
  }

  // ---- fused epilogue ----
  if (n0 >= 2048) {
    // V blocks: bias only, u16x4 stores along n (= m)
#pragma unroll
    for (int mf = 0; mf < 8; ++mf) {
#pragma unroll
      for (int j = 0; j < 4; ++j) {
        const int ncol = n0 + wc * 64 + j * 16 + lr;
        const int hh = (ncol & 1023) >> 6;
        const int d = j * 16 + lr;
        const float bias_v = bias[ncol];
        const int m = m0 + wr * 128 + mf * 16 + lq * 4;  // base of 4 consecutive
        const int bb = m >> 9, nB = m & 511;
        u16x4 vv;
#pragma unroll
        for (int r = 0; r < 4; ++r) vv[r] = f2bf(acc[mf][j][r] + bias_v);
        *(u16x4*)(Vtb + ((size_t)(bb * H_ + hh) * D_ + d) * N_ + nB) = vv;
      }
    }
  } else {
    // Q/K blocks: elu+1 (__expf), rope (Q also *1/8); float2 table loads
    const bool isQ = (n0 < 1024);
#pragma unroll
    for (int mf = 0; mf < 8; ++mf) {
#pragma unroll
      for (int j = 0; j < 4; ++j) {
        const int ncol = n0 + wc * 64 + j * 16 + lr;
        const int hh = (ncol & 1023) >> 6;
        const int d = ncol & 63;
        const float bias_v = bias[ncol];
        const int ip = d >> 1;
#pragma unroll
        for (int r = 0; r < 4; ++r) {
          const int m = m0 + wr * 128 + mf * 16 + lq * 4 + r;
          const int bb = m >> 9, n = m & 511;
          const float val = acc[mf][j][r] + bias_v;
          const float e = val > 0.f ? val + 1.f : __expf(val);  // elu+1
          const float partner = __shfl_xor(e, 1);
          const float2 sc = sc_t[n * 32 + ip];
          float o = (d & 1) ? (partner * sc.x + e * sc.y) : (e * sc.y - partner * sc.x);
          if (isQ) o *= 0.125f;  // fold 1/sqrt(D) into Q
          unsigned short* dst = isQ ? Qb : Kb;
          dst[((size_t)(bb * H_ + hh) * N_ + n) * D_ + d] = f2bf(o);
        }
      }
    }
  }
}

// ---------- attention + lepe : one block per (b,h) (best-known R17 form) ----------
__global__ __launch_bounds__(512, 2) void attn_kernel(
    const unsigned short* __restrict__ Qb, const unsigned short* __restrict__ Kb,
    const unsigned short* __restrict__ Vtb,
    const float* __restrict__ w_lepe, const float* __restrict__ b_lepe,
    float* __restrict__ out) {
  __shared__ unsigned short Ks[512 * 64];      // 64 KB
  __shared__ unsigned short Vs[64 * 512];      // 64 KB
  __shared__ unsigned short Pb[8 * 2 * 1024];  // 32 KB: per wave 2 bufs x [16][64]
  const int t = threadIdx.x, wv = t >> 6, l = t & 63;
  const int lq = l >> 4, lr = l & 15;
  const int bh = blockIdx.x;           // 0..511
  const int bb = bh >> 4, h = bh & 15;
  const size_t base = (size_t)bh * (N_ * D_);

  {
    const int row8 = t >> 3, ch = t & 7;
#pragma unroll
    for (int c = 0; c < 8; ++c) {
      const int r = c * 64 + row8;
      const int sch = ch ^ (r & 7);
      glds16(Kb + base + (size_t)r * D_ + sch * 8, Ks + c * 4096 + t * 8);
    }
  }
  {
    const int ch = t & 63;
#pragma unroll
    for (int c = 0; c < 8; ++c) {
      const int d = c * 8 + wv;
      const int sch = ch ^ (d & 7);
      glds16(Vtb + base + (size_t)d * N_ + sch * 8, Vs + c * 4096 + t * 8);
    }
  }

  asm volatile("s_waitcnt vmcnt(8)" ::: "memory");
  __builtin_amdgcn_s_barrier();

  unsigned short* PwA = Pb + wv * 2048;  // buf0 [16 q][64 k], 16B-slot swizzle
  unsigned short* PwB = PwA + 1024;      // buf1

#define PWRITE(ccv, Pdst)                                                        \
  do {                                                                           \
    _Pragma("unroll") for (int kl = 0; kl < 4; ++kl) {                           \
      const int kt_ = (ccv) * 4 + kl;                                            \
      u16x4 pk;                                                                  \
      _Pragma("unroll") for (int r = 0; r < 4; ++r) pk[r] = f2bf(s[kt_][r] * inv); \
      const int slot = kl * 2 + (lq >> 1);                                       \
      *(u16x4*)((Pdst) + lr * 64 + ((slot ^ (lr & 7)) << 3) + (lq & 1) * 4) = pk; \
    }                                                                            \
  } while (0)

  // Q prefetch: load p=0 before the loop; issue p+1 right after the S-loop
  bf16x8 qf0 = *(const bf16x8*)(Qb + base + (size_t)(wv * 64 + lr) * D_ + lq * 8);
  bf16x8 qf1 = *(const bf16x8*)(Qb + base + (size_t)(wv * 64 + lr) * D_ + 32 + lq * 8);

  for (int p = 0; p < 4; ++p) {
    const int ql = wv * 64 + p * 16;

    // S^T via swapped mfma(K,Q): s[kt][r] = S[q=ql+lr][k=kt*16+lq*4+r]
    f32x4 s[32];
#pragma unroll
    for (int kt = 0; kt < 32; ++kt) {
      const int r = kt * 16 + lr;
      const int rx = r & 7;
      const unsigned short* kr = Ks + r * 64;
      const bf16x8 kf0 = *(const bf16x8*)(kr + (lq ^ rx) * 8);
      const bf16x8 kf1 = *(const bf16x8*)(kr + ((lq + 4) ^ rx) * 8);
      f32x4 a = {0.f, 0.f, 0.f, 0.f};
      a = MFMA16(kf0, qf0, a);
      a = MFMA16(kf1, qf1, a);
      s[kt] = a;
    }

    // prefetch next p's Q (hides L2 latency under softmax+PV)
    if (p < 3) {
      const int qn = ql + 16;
      qf0 = *(const bf16x8*)(Qb + base + (size_t)(qn + lr) * D_ + lq * 8);
      qf1 = *(const bf16x8*)(Qb + base + (size_t)(qn + lr) * D_ + 32 + lq * 8);
    }

    // softmax for row q=ql+lr: 8 parallel accumulator chains, then combine
    float macc[8];
#pragma unroll
    for (int i = 0; i < 8; ++i) macc[i] = -1e30f;
#pragma unroll
    for (int kt = 0; kt < 32; ++kt)
#pragma unroll
      for (int r = 0; r < 4; ++r)
        macc[(kt & 1) * 4 + r] = fmaxf(macc[(kt & 1) * 4 + r], s[kt][r]);
#pragma unroll
    for (int i = 0; i < 4; ++i) macc[i] = fmaxf(macc[i], macc[i + 4]);
    macc[0] = fmaxf(macc[0], macc[1]);
    macc[2] = fmaxf(macc[2], macc[3]);
    float m = fmaxf(macc[0], macc[2]);
    m = fmaxf(m, __shfl_xor(m, 16));
    m = fmaxf(m, __shfl_xor(m, 32));

    float sacc[8];
#pragma unroll
    for (int i = 0; i < 8; ++i) sacc[i] = 0.f;
#pragma unroll
    for (int kt = 0; kt < 32; ++kt)
#pragma unroll
      for (int r = 0; r < 4; ++r) {
        const float pv = __expf(s[kt][r] - m);   // scale pre-folded into Q
        s[kt][r] = pv;
        sacc[(kt & 1) * 4 + r] += pv;
      }
#pragma unroll
    for (int i = 0; i < 4; ++i) sacc[i] += sacc[i + 4];
    sacc[0] += sacc[1];
    sacc[2] += sacc[3];
    float su = sacc[0] + sacc[2];
    su += __shfl_xor(su, 16);
    su += __shfl_xor(su, 32);
    const float inv = 1.0f / su;

    if (p == 0) __syncthreads();  // V staged (drains vmcnt); all waves reach once

    // PV: 8 chunks of 64 k through double-buffered P; counted RAW wait only.
    f32x4 o[4] = {};
    PWRITE(0, PwA);
#pragma unroll
    for (int cc = 0; cc < 8; ++cc) {
      unsigned short* bufC = (cc & 1) ? PwB : PwA;
      unsigned short* bufN = (cc & 1) ? PwA : PwB;
      if (cc < 7) PWRITE(cc + 1, bufN);
      // in-order DS queue: <=4 outstanding == next chunk's writes => cc's retired
      asm volatile("s_waitcnt lgkmcnt(4)" ::: "memory");
#pragma unroll
      for (int w = 0; w < 2; ++w) {
        const u16x8 pr =
            *(const u16x8*)(bufC + lr * 64 + (((w * 4 + lq) ^ (lr & 7)) << 3));
        const bf16x8 pf = as_bf16x8(pr);
        const int ci = cc * 8 + w * 4 + lq;
#pragma unroll
        for (int j2 = 0; j2 < 4; j2++) {
          const int dr = j2 * 16 + lr;
          const bf16x8 vf = *(const bf16x8*)(Vs + dr * 512 + ((ci ^ (dr & 7)) << 3));
          o[j2] = MFMA16(pf, vf, o[j2]);
        }
      }
    }

    // epilogue: + lepe (depthwise conv3 over n from resident Vs); write fp32
#pragma unroll
    for (int j2 = 0; j2 < 4; j2++) {
      const int d = j2 * 16 + lr;
      const int c = h * 64 + d;
      const float w0 = w_lepe[c * 3 + 0], w1 = w_lepe[c * 3 + 1], w2 = w_lepe[c * 3 + 2];
      const float bl = b_lepe[c];
      const int dx = d & 7;
#pragma unroll
      for (int r = 0; r < 4; r++) {
        const int n = ql + lq * 4 + r;
        float vm1 = 0.f, vp1 = 0.f;
        if (n > 0) {
          const int nn = n - 1;
          vm1 = bf2f(Vs[d * 512 + (((nn >> 3) ^ dx) << 3) + (nn & 7)]);
        }
        const float v0 = bf2f(Vs[d * 512 + (((n >> 3) ^ dx) << 3) + (n & 7)]);
        if (n < 511) {
          const int nn = n + 1;
          vp1 = bf2f(Vs[d * 512 + (((nn >> 3) ^ dx) << 3) + (nn & 7)]);
        }
        const float lepe = vm1 * w0 + v0 * w1 + vp1 * w2 + bl;
        out[((size_t)(bb * N_ + n)) * C_ + c] = o[j2][r] + lepe;
      }
    }
  }
#undef PWRITE
}

// ---------- launcher ----------
extern "C" void kernel_launch(void* const* d_in, const int* in_sizes, int n_in,
                              void* d_out, int out_size, void* d_ws, size_t ws_size,
                              hipStream_t stream) {
  (void)in_sizes; (void)n_in; (void)out_size; (void)ws_size;
  const float* x = (const float*)d_in[0];
  const float* w_qkv = (const float*)d_in[1];
  const float* b_qkv = (const float*)d_in[2];
  const float* w_lepe = (const float*)d_in[3];
  const float* b_lepe = (const float*)d_in[4];
  float* out = (float*)d_out;

  unsigned short* ws = (unsigned short*)d_ws;
  unsigned short* xb = ws;                          // 16777216 el
  unsigned short* wb = xb + 16777216;               // 3145728 el
  unsigned short* Qb = wb + 3145728;                // 16777216 el
  unsigned short* Kb = Qb + 16777216;               // 16777216 el
  unsigned short* Vtb = Kb + 16777216;              // 16777216 el
  float2* sc_t = (float2*)(Vtb + 16777216);         // 16384 float2

  const int prep_units = NX8 + NW8 + NT8;           // 2,492,416
  prep_kernel<<<(prep_units + 255) / 256, 256, 0, stream>>>(x, w_qkv, xb, wb, sc_t);
  qkv_gemm_kernel<<<768, 512, 0, stream>>>(xb, wb, b_qkv, Qb, Kb, Vtb, sc_t);
  attn_kernel<<<512, 512, 0, stream>>>(Qb, Kb, Vtb, w_lepe, b_lepe, out);
}

// Round 21
// 216.848 us; speedup vs baseline: 1.0891x; 1.0369x over previous
//
#include <hip/hip_runtime.h>
#include <stdint.h>

// ---------- types ----------
typedef __attribute__((ext_vector_type(8))) __bf16 bf16x8;
typedef __attribute__((ext_vector_type(4))) float f32x4;
typedef __attribute__((ext_vector_type(8))) unsigned short u16x8;
typedef __attribute__((ext_vector_type(4))) unsigned short u16x4;

#define MFMA16(a, b, c) __builtin_amdgcn_mfma_f32_16x16x32_bf16((a), (b), (c), 0, 0, 0)

__device__ __forceinline__ void glds16(const void* g, void* l) {
  __builtin_amdgcn_global_load_lds(
      (const __attribute__((address_space(1))) void*)(uintptr_t)g,
      (__attribute__((address_space(3))) void*)(uint32_t)(uintptr_t)l,
      16, 0, 0);
}

__device__ __forceinline__ unsigned short f2bf(float f) {
  union { float f; unsigned u; } v; v.f = f;
  unsigned r = v.u + 0x7FFFu + ((v.u >> 16) & 1u);
  return (unsigned short)(r >> 16);
}
__device__ __forceinline__ float bf2f(unsigned short s) {
  union { unsigned u; float f; } v; v.u = ((unsigned)s) << 16;
  return v.f;
}
__device__ __forceinline__ bf16x8 as_bf16x8(u16x8 v) {
  union { u16x8 u; bf16x8 b; } c; c.u = v; return c.b;
}

// ---------- problem constants ----------
#define B_ 32
#define N_ 512
#define C_ 1024
#define H_ 16
#define D_ 64
#define K_ C_                // 1024

#define NX8 2097152          // x elements / 8
#define NW8 393216           // w elements / 8
#define NT8 2048             // table entries / 8

// ---------- fused prep: x->bf16 | w->bf16 | rope float2 table, one launch ----------
__global__ __launch_bounds__(256) void prep_kernel(
    const float* __restrict__ x, const float* __restrict__ w,
    unsigned short* __restrict__ xb, unsigned short* __restrict__ wb,
    float2* __restrict__ sc_t) {
  const int i = blockIdx.x * 256 + threadIdx.x;
  if (i < NX8 + NW8) {
    const float* src = (i < NX8) ? x : w;
    unsigned short* dst = (i < NX8) ? xb : wb;
    const int k = (i < NX8) ? i : i - NX8;
    const float4* p = reinterpret_cast<const float4*>(src) + (size_t)k * 2;
    float4 a = p[0], b = p[1];
    u16x8 o;
    o[0] = f2bf(a.x); o[1] = f2bf(a.y); o[2] = f2bf(a.z); o[3] = f2bf(a.w);
    o[4] = f2bf(b.x); o[5] = f2bf(b.y); o[6] = f2bf(b.z); o[7] = f2bf(b.w);
    *reinterpret_cast<u16x8*>(dst + (size_t)k * 8) = o;
  } else if (i < NX8 + NW8 + NT8) {
    const int base = (i - NX8 - NW8) * 8;
#pragma unroll
    for (int e = 0; e < 8; ++e) {
      const int idx = base + e;           // n*32 + ip
      const int n = idx >> 5, ip = idx & 31;
      const float div = expf(-(2.0f * (float)ip) * (9.210340371976184f / 64.0f));
      const float ang = (float)n * div;
      sc_t[idx] = make_float2(sinf(ang), cosf(ang));
    }
  }
}

// ---------- QKV GEMM: 256x256, BK=64; A-triple/B-double, counted vmcnt (R20) ----------
// NEW (R21): u-loop fully unrolled -> buffer rotation is compile-time, every
// ds_read offset becomes an immediate (kills ~30 VALU addr ops/tile).
#define STAGE_A(dstoff, uu)                                            \
  do {                                                                 \
    _Pragma("unroll") for (int h_ = 0; h_ < 4; ++h_)                   \
      glds16(aS[h_] + (size_t)(uu) * 64,                               \
             &lds[(dstoff) + h_ * 4096 + t * 8]);                      \
  } while (0)
#define STAGE_B(dstoff, uu)                                            \
  do {                                                                 \
    _Pragma("unroll") for (int h_ = 0; h_ < 4; ++h_)                   \
      glds16(bS[h_] + (size_t)(uu) * 64,                               \
             &lds[(dstoff) + h_ * 4096 + t * 8]);                      \
  } while (0)

__global__ __launch_bounds__(512, 2) void qkv_gemm_kernel(
    const unsigned short* __restrict__ xb, const unsigned short* __restrict__ wb,
    const float* __restrict__ bias,
    unsigned short* __restrict__ Qb, unsigned short* __restrict__ Kb,
    unsigned short* __restrict__ Vtb,
    const float2* __restrict__ sc_t) {
  __shared__ unsigned short lds[81920];  // 160 KB
  const int t = threadIdx.x;
  const int wv = t >> 6, l = t & 63;
  const int wr = wv >> 2, wc = wv & 3;   // 2 x 4 waves, wave tile 128x64
  const int lq = l >> 4, lr = l & 15;

  // XCD-chunked bijective swizzle (768 = 8 * 96)
  const int bid = (blockIdx.x & 7) * 96 + (blockIdx.x >> 3);
  const int mBlk = bid / 12, nBlk = bid % 12;
  const int m0 = mBlk * 256, n0 = nBlk * 256;

  // staging source pointers (global chunk pre-swizzled; LDS dest linear)
  const int rl = t >> 3;                       // 0..63
  const int cw = ((t & 7) ^ (rl & 7)) * 8;     // swizzled source chunk (halfwords)
  const unsigned short* aS[4];
  const unsigned short* bS[4];
#pragma unroll
  for (int h = 0; h < 4; ++h) {
    aS[h] = xb + (size_t)(m0 + h * 64 + rl) * K_ + cw;
    bS[h] = wb + (size_t)(n0 + h * 64 + rl) * K_ + cw;
  }

  // fragment read offsets within a buffer (halfwords)
  const int aBase = (wr * 128 + lr) * 64;
  const int bBase = (wc * 64 + lr) * 64;
  int chs[2];
#pragma unroll
  for (int s = 0; s < 2; ++s) chs[s] = ((s * 4 + lq) ^ (lr & 7)) * 8;

  f32x4 acc[8][4] = {};

  // prologue: A(0), B(0), A(1)  [issue order = age order]
  STAGE_A(0, 0);
  STAGE_B(49152, 0);
  STAGE_A(16384, 1);

  // full unroll: buffer offsets compile-time (A rotation period 3, B period 2)
#pragma unroll
  for (int u = 0; u < 16; ++u) {
    const int aCur = (u % 3) * 16384;
    const int aNx2 = ((u + 2) % 3) * 16384;
    const int bCur = 49152 + (u & 1) * 16384;
    const int bNxt = 49152 + ((u + 1) & 1) * 16384;

    if (u == 15) asm volatile("s_waitcnt vmcnt(0)" ::: "memory");
    else         asm volatile("s_waitcnt vmcnt(4)" ::: "memory");
    __builtin_amdgcn_s_barrier();

    // stage ahead: B first (youngest-needed discipline), then A
    if (u + 1 < 16) STAGE_B(bNxt, u + 1);
    if (u + 2 < 16) STAGE_A(aNx2, u + 2);

    const unsigned short* La = &lds[aCur];
    const unsigned short* Lb = &lds[bCur];
    bf16x8 afr[8][2], bfr[4][2];
#pragma unroll
    for (int mf = 0; mf < 8; ++mf)
#pragma unroll
      for (int s = 0; s < 2; ++s)
        afr[mf][s] = *(const bf16x8*)(La + aBase + mf * 1024 + chs[s]);
#pragma unroll
    for (int j = 0; j < 4; ++j)
#pragma unroll
      for (int s = 0; s < 2; ++s)
        bfr[j][s] = *(const bf16x8*)(Lb + bBase + j * 1024 + chs[s]);

#pragma unroll
    for (int mf = 0; mf < 8; ++mf)
#pragma unroll
      for (int j = 0; j < 4; ++j)
#pragma unroll
        for (int s = 0; s < 2; ++s)
          acc[mf][j] = MFMA16(afr[mf][s], bfr[j][s], acc[mf][j]);
  }

  // ---- fused epilogue ----
  if (n0 >= 2048) {
    // V blocks: bias only, u16x4 stores along n (= m)
#pragma unroll
    for (int mf = 0; mf < 8; ++mf) {
#pragma unroll
      for (int j = 0; j < 4; ++j) {
        const int ncol = n0 + wc * 64 + j * 16 + lr;
        const int hh = (ncol & 1023) >> 6;
        const int d = j * 16 + lr;
        const float bias_v = bias[ncol];
        const int m = m0 + wr * 128 + mf * 16 + lq * 4;  // base of 4 consecutive
        const int bb = m >> 9, nB = m & 511;
        u16x4 vv;
#pragma unroll
        for (int r = 0; r < 4; ++r) vv[r] = f2bf(acc[mf][j][r] + bias_v);
        *(u16x4*)(Vtb + ((size_t)(bb * H_ + hh) * D_ + d) * N_ + nB) = vv;
      }
    }
  } else {
    // Q/K blocks: elu+1 (__expf), rope (Q also *1/8); float2 table loads
    const bool isQ = (n0 < 1024);
#pragma unroll
    for (int mf = 0; mf < 8; ++mf) {
#pragma unroll
      for (int j = 0; j < 4; ++j) {
        const int ncol = n0 + wc * 64 + j * 16 + lr;
        const int hh = (ncol & 1023) >> 6;
        const int d = ncol & 63;
        const float bias_v = bias[ncol];
        const int ip = d >> 1;
#pragma unroll
        for (int r = 0; r < 4; ++r) {
          const int m = m0 + wr * 128 + mf * 16 + lq * 4 + r;
          const int bb = m >> 9, n = m & 511;
          const float val = acc[mf][j][r] + bias_v;
          const float e = val > 0.f ? val + 1.f : __expf(val);  // elu+1
          const float partner = __shfl_xor(e, 1);
          const float2 sc = sc_t[n * 32 + ip];
          float o = (d & 1) ? (partner * sc.x + e * sc.y) : (e * sc.y - partner * sc.x);
          if (isQ) o *= 0.125f;  // fold 1/sqrt(D) into Q
          unsigned short* dst = isQ ? Qb : Kb;
          dst[((size_t)(bb * H_ + hh) * N_ + n) * D_ + d] = f2bf(o);
        }
      }
    }
  }
}

// ---------- attention + lepe : one block per (b,h) (unchanged from R20) ----------
__global__ __launch_bounds__(512, 2) void attn_kernel(
    const unsigned short* __restrict__ Qb, const unsigned short* __restrict__ Kb,
    const unsigned short* __restrict__ Vtb,
    const float* __restrict__ w_lepe, const float* __restrict__ b_lepe,
    float* __restrict__ out) {
  __shared__ unsigned short Ks[512 * 64];      // 64 KB
  __shared__ unsigned short Vs[64 * 512];      // 64 KB
  __shared__ unsigned short Pb[8 * 2 * 1024];  // 32 KB: per wave 2 bufs x [16][64]
  const int t = threadIdx.x, wv = t >> 6, l = t & 63;
  const int lq = l >> 4, lr = l & 15;
  const int bh = blockIdx.x;           // 0..511
  const int bb = bh >> 4, h = bh & 15;
  const size_t base = (size_t)bh * (N_ * D_);

  {
    const int row8 = t >> 3, ch = t & 7;
#pragma unroll
    for (int c = 0; c < 8; ++c) {
      const int r = c * 64 + row8;
      const int sch = ch ^ (r & 7);
      glds16(Kb + base + (size_t)r * D_ + sch * 8, Ks + c * 4096 + t * 8);
    }
  }
  {
    const int ch = t & 63;
#pragma unroll
    for (int c = 0; c < 8; ++c) {
      const int d = c * 8 + wv;
      const int sch = ch ^ (d & 7);
      glds16(Vtb + base + (size_t)d * N_ + sch * 8, Vs + c * 4096 + t * 8);
    }
  }

  asm volatile("s_waitcnt vmcnt(8)" ::: "memory");
  __builtin_amdgcn_s_barrier();

  unsigned short* PwA = Pb + wv * 2048;  // buf0 [16 q][64 k], 16B-slot swizzle
  unsigned short* PwB = PwA + 1024;      // buf1

#define PWRITE(ccv, Pdst)                                                        \
  do {                                                                           \
    _Pragma("unroll") for (int kl = 0; kl < 4; ++kl) {                           \
      const int kt_ = (ccv) * 4 + kl;                                            \
      u16x4 pk;                                                                  \
      _Pragma("unroll") for (int r = 0; r < 4; ++r) pk[r] = f2bf(s[kt_][r] * inv); \
      const int slot = kl * 2 + (lq >> 1);                                       \
      *(u16x4*)((Pdst) + lr * 64 + ((slot ^ (lr & 7)) << 3) + (lq & 1) * 4) = pk; \
    }                                                                            \
  } while (0)

  // Q prefetch: load p=0 before the loop; issue p+1 right after the S-loop
  bf16x8 qf0 = *(const bf16x8*)(Qb + base + (size_t)(wv * 64 + lr) * D_ + lq * 8);
  bf16x8 qf1 = *(const bf16x8*)(Qb + base + (size_t)(wv * 64 + lr) * D_ + 32 + lq * 8);

  for (int p = 0; p < 4; ++p) {
    const int ql = wv * 64 + p * 16;

    // S^T via swapped mfma(K,Q): s[kt][r] = S[q=ql+lr][k=kt*16+lq*4+r]
    f32x4 s[32];
#pragma unroll
    for (int kt = 0; kt < 32; ++kt) {
      const int r = kt * 16 + lr;
      const int rx = r & 7;
      const unsigned short* kr = Ks + r * 64;
      const bf16x8 kf0 = *(const bf16x8*)(kr + (lq ^ rx) * 8);
      const bf16x8 kf1 = *(const bf16x8*)(kr + ((lq + 4) ^ rx) * 8);
      f32x4 a = {0.f, 0.f, 0.f, 0.f};
      a = MFMA16(kf0, qf0, a);
      a = MFMA16(kf1, qf1, a);
      s[kt] = a;
    }

    // prefetch next p's Q (hides L2 latency under softmax+PV)
    if (p < 3) {
      const int qn = ql + 16;
      qf0 = *(const bf16x8*)(Qb + base + (size_t)(qn + lr) * D_ + lq * 8);
      qf1 = *(const bf16x8*)(Qb + base + (size_t)(qn + lr) * D_ + 32 + lq * 8);
    }

    // softmax for row q=ql+lr: 8 parallel accumulator chains, then combine
    float macc[8];
#pragma unroll
    for (int i = 0; i < 8; ++i) macc[i] = -1e30f;
#pragma unroll
    for (int kt = 0; kt < 32; ++kt)
#pragma unroll
      for (int r = 0; r < 4; ++r)
        macc[(kt & 1) * 4 + r] = fmaxf(macc[(kt & 1) * 4 + r], s[kt][r]);
#pragma unroll
    for (int i = 0; i < 4; ++i) macc[i] = fmaxf(macc[i], macc[i + 4]);
    macc[0] = fmaxf(macc[0], macc[1]);
    macc[2] = fmaxf(macc[2], macc[3]);
    float m = fmaxf(macc[0], macc[2]);
    m = fmaxf(m, __shfl_xor(m, 16));
    m = fmaxf(m, __shfl_xor(m, 32));

    float sacc[8];
#pragma unroll
    for (int i = 0; i < 8; ++i) sacc[i] = 0.f;
#pragma unroll
    for (int kt = 0; kt < 32; ++kt)
#pragma unroll
      for (int r = 0; r < 4; ++r) {
        const float pv = __expf(s[kt][r] - m);   // scale pre-folded into Q
        s[kt][r] = pv;
        sacc[(kt & 1) * 4 + r] += pv;
      }
#pragma unroll
    for (int i = 0; i < 4; ++i) sacc[i] += sacc[i + 4];
    sacc[0] += sacc[1];
    sacc[2] += sacc[3];
    float su = sacc[0] + sacc[2];
    su += __shfl_xor(su, 16);
    su += __shfl_xor(su, 32);
    const float inv = 1.0f / su;

    if (p == 0) __syncthreads();  // V staged (drains vmcnt); all waves reach once

    // PV: 8 chunks of 64 k through double-buffered P; counted RAW wait only.
    f32x4 o[4] = {};
    PWRITE(0, PwA);
#pragma unroll
    for (int cc = 0; cc < 8; ++cc) {
      unsigned short* bufC = (cc & 1) ? PwB : PwA;
      unsigned short* bufN = (cc & 1) ? PwA : PwB;
      if (cc < 7) PWRITE(cc + 1, bufN);
      // in-order DS queue: <=4 outstanding == next chunk's writes => cc's retired
      asm volatile("s_waitcnt lgkmcnt(4)" ::: "memory");
#pragma unroll
      for (int w = 0; w < 2; ++w) {
        const u16x8 pr =
            *(const u16x8*)(bufC + lr * 64 + (((w * 4 + lq) ^ (lr & 7)) << 3));
        const bf16x8 pf = as_bf16x8(pr);
        const int ci = cc * 8 + w * 4 + lq;
#pragma unroll
        for (int j2 = 0; j2 < 4; j2++) {
          const int dr = j2 * 16 + lr;
          const bf16x8 vf = *(const bf16x8*)(Vs + dr * 512 + ((ci ^ (dr & 7)) << 3));
          o[j2] = MFMA16(pf, vf, o[j2]);
        }
      }
    }

    // epilogue: + lepe (depthwise conv3 over n from resident Vs); write fp32
#pragma unroll
    for (int j2 = 0; j2 < 4; j2++) {
      const int d = j2 * 16 + lr;
      const int c = h * 64 + d;
      const float w0 = w_lepe[c * 3 + 0], w1 = w_lepe[c * 3 + 1], w2 = w_lepe[c * 3 + 2];
      const float bl = b_lepe[c];
      const int dx = d & 7;
#pragma unroll
      for (int r = 0; r < 4; r++) {
        const int n = ql + lq * 4 + r;
        float vm1 = 0.f, vp1 = 0.f;
        if (n > 0) {
          const int nn = n - 1;
          vm1 = bf2f(Vs[d * 512 + (((nn >> 3) ^ dx) << 3) + (nn & 7)]);
        }
        const float v0 = bf2f(Vs[d * 512 + (((n >> 3) ^ dx) << 3) + (n & 7)]);
        if (n < 511) {
          const int nn = n + 1;
          vp1 = bf2f(Vs[d * 512 + (((nn >> 3) ^ dx) << 3) + (nn & 7)]);
        }
        const float lepe = vm1 * w0 + v0 * w1 + vp1 * w2 + bl;
        out[((size_t)(bb * N_ + n)) * C_ + c] = o[j2][r] + lepe;
      }
    }
  }
#undef PWRITE
}

// ---------- launcher ----------
extern "C" void kernel_launch(void* const* d_in, const int* in_sizes, int n_in,
                              void* d_out, int out_size, void* d_ws, size_t ws_size,
                              hipStream_t stream) {
  (void)in_sizes; (void)n_in; (void)out_size; (void)ws_size;
  const float* x = (const float*)d_in[0];
  const float* w_qkv = (const float*)d_in[1];
  const float* b_qkv = (const float*)d_in[2];
  const float* w_lepe = (const float*)d_in[3];
  const float* b_lepe = (const float*)d_in[4];
  float* out = (float*)d_out;

  unsigned short* ws = (unsigned short*)d_ws;
  unsigned short* xb = ws;                          // 16777216 el
  unsigned short* wb = xb + 16777216;               // 3145728 el
  unsigned short* Qb = wb + 3145728;                // 16777216 el
  unsigned short* Kb = Qb + 16777216;               // 16777216 el
  unsigned short* Vtb = Kb + 16777216;              // 16777216 el
  float2* sc_t = (float2*)(Vtb + 16777216);         // 16384 float2

  const int prep_units = NX8 + NW8 + NT8;           // 2,492,416
  prep_kernel<<<(prep_units + 255) / 256, 256, 0, stream>>>(x, w_qkv, xb, wb, sc_t);
  qkv_gemm_kernel<<<768, 512, 0, stream>>>(xb, wb, b_qkv, Qb, Kb, Vtb, sc_t);
  attn_kernel<<<512, 512, 0, stream>>>(Qb, Kb, Vtb, w_lepe, b_lepe, out);
}